// Round 6
// baseline (200.162 us; speedup 1.0000x reference)
//
#include <hip/hip_runtime.h>
#include <hip/hip_bf16.h>
#include <stdint.h>

typedef __bf16 bf16x8 __attribute__((ext_vector_type(8)));
typedef float f32x4 __attribute__((ext_vector_type(4)));

#define MAXD 40
#define ND   81
#define CSZ  256
#define HSZ  128
#define WSZ  416
#define HW   (HSZ * WSZ)

// Banded GEMM, streaming form. u-tile index p in [0,30], u0(p) = 16p - 40.
// Tile (r, j): A rows w in [16r,16r+16), B rows u in [16(r+j)-40, ...+16), p = r+j.
// For fixed p the B fragment is shared by all 6 tiles (r = p-5..p).
// Wave owns p-pair {p0, p0+1}: 12 acc tiles, 7 A-frags + 2 R-frags per chunk.
// No LDS, no barriers: pure load->cvt->MFMA stream.

__global__ __launch_bounds__(512, 4)
void corr_stream_kernel(const float* __restrict__ L,
                        const float* __restrict__ R,
                        float* __restrict__ out) {
    const int t   = threadIdx.x;
    const int wv  = t >> 6;      // 0..7
    const int l   = t & 63;
    const int l15 = l & 15;
    const int l4  = l >> 4;      // 0..3

    const int bh = blockIdx.x >> 1;   // g-blocks of same (b,h) adjacent -> same XCD
    const int g  = blockIdx.x & 1;
    const int b  = bh >> 7;
    const int h  = bh & 127;

    const int pairIdx = 8 * g + wv;      // 0..15
    const int p0      = 2 * pairIdx;     // 0,2,...,30
    const bool hasP1  = (p0 + 1 <= 30);
    const int u0      = 16 * p0 - MAXD;

    const size_t slab = ((size_t)b * CSZ) * HW + (size_t)h * WSZ;
    const float* Lp = L + slab;
    const float* Rp = R + slab;

    f32x4 acc0[6], acc1[6];
    #pragma unroll
    for (int a = 0; a < 6; ++a) { acc0[a] = (f32x4)0.0f; acc1[a] = (f32x4)0.0f; }

    #pragma unroll 2
    for (int ck = 0; ck < 8; ++ck) {
        const size_t cbase = (size_t)(32 * ck + 8 * l4) * HW;  // lane's channel slice
        const float* Lc = Lp + cbase;
        const float* Rc = Rp + cbase;

        // ---- R fragments (shared across the 6 tiles of each p) ----
        bf16x8 rf0, rf1;
        {
            const int u = u0 + l15;
            const bool inb = (unsigned)u < (unsigned)WSZ;
            const int uc = inb ? u : 0;
            float tmp[8];
            #pragma unroll
            for (int kk = 0; kk < 8; ++kk) tmp[kk] = Rc[(size_t)kk * HW + uc];
            #pragma unroll
            for (int kk = 0; kk < 8; ++kk) rf0[kk] = (__bf16)(inb ? tmp[kk] : 0.0f);
        }
        if (hasP1) {
            const int u = u0 + 16 + l15;
            const bool inb = (unsigned)u < (unsigned)WSZ;
            const int uc = inb ? u : 0;
            float tmp[8];
            #pragma unroll
            for (int kk = 0; kk < 8; ++kk) tmp[kk] = Rc[(size_t)kk * HW + uc];
            #pragma unroll
            for (int kk = 0; kk < 8; ++kk) rf1[kk] = (__bf16)(inb ? tmp[kk] : 0.0f);
        }

        // ---- A fragments, interleaved with MFMA (short live ranges) ----
        #pragma unroll
        for (int a = 0; a < 7; ++a) {
            const int r = p0 - 5 + a;
            if (r >= 0 && r <= 25) {
                const int w = 16 * r + l15;
                float tmp[8];
                #pragma unroll
                for (int kk = 0; kk < 8; ++kk) tmp[kk] = Lc[(size_t)kk * HW + w];
                bf16x8 af;
                #pragma unroll
                for (int kk = 0; kk < 8; ++kk) af[kk] = (__bf16)tmp[kk];
                if (a < 6)
                    acc0[a] = __builtin_amdgcn_mfma_f32_16x16x32_bf16(af, rf0, acc0[a], 0, 0, 0);
                if (hasP1 && a >= 1)
                    acc1[a - 1] = __builtin_amdgcn_mfma_f32_16x16x32_bf16(af, rf1, acc1[a - 1], 0, 0, 0);
            }
        }
    }

    // ---- epilogue: validated mapping, d = 16j + n - m; n=l15, m=4*l4+rr ----
    const float scale = 1.0f / 256.0f;
    const size_t outbase = ((size_t)b * ND) * HW + (size_t)h * WSZ;

    #pragma unroll
    for (int a = 0; a < 6; ++a) {
        const int r = p0 - 5 + a;
        if (r >= 0 && r <= 25) {
            const int j = 5 - a;    // p0 = r + j
            #pragma unroll
            for (int rr = 0; rr < 4; ++rr) {
                const int m = 4 * l4 + rr;
                const int d = 16 * j + l15 - m;
                if ((unsigned)d < (unsigned)ND)
                    out[outbase + (size_t)d * HW + 16 * r + m] = acc0[a][rr] * scale;
            }
        }
    }
    if (hasP1) {
        #pragma unroll
        for (int a = 1; a < 7; ++a) {
            const int r = p0 - 5 + a;
            if (r >= 0 && r <= 25) {
                const int j = 6 - a;    // p0+1 = r + j
                #pragma unroll
                for (int rr = 0; rr < 4; ++rr) {
                    const int m = 4 * l4 + rr;
                    const int d = 16 * j + l15 - m;
                    if ((unsigned)d < (unsigned)ND)
                        out[outbase + (size_t)d * HW + 16 * r + m] = acc1[a - 1][rr] * scale;
                }
            }
        }
    }
}

extern "C" void kernel_launch(void* const* d_in, const int* in_sizes, int n_in,
                              void* d_out, int out_size, void* d_ws, size_t ws_size,
                              hipStream_t stream) {
    const float* left  = (const float*)d_in[0];
    const float* right = (const float*)d_in[1];
    float* out = (float*)d_out;
    (void)in_sizes; (void)n_in; (void)out_size; (void)d_ws; (void)ws_size;
    corr_stream_kernel<<<dim3(2 * 4 * 128), dim3(512), 0, stream>>>(left, right, out);
}

// Round 7
// 119.646 us; speedup vs baseline: 1.6729x; 1.6729x over previous
//
#include <hip/hip_runtime.h>
#include <hip/hip_bf16.h>
#include <stdint.h>

typedef __bf16 bf16x8 __attribute__((ext_vector_type(8)));
typedef float f32x4 __attribute__((ext_vector_type(4)));

#define MAXD 40
#define ND   81
#define CSZ  256
#define HSZ  128
#define WSZ  416
#define HW   (HSZ * WSZ)
#define RSTW 20            // dwords per LDS row (= 40 bf16: 32 data + 8 pad)
#define NCHUNK 8

static __device__ __forceinline__ uint32_t pk2(float a, float b) {
    union { __bf16 h[2]; uint32_t u; } v;
    v.h[0] = (__bf16)a; v.h[1] = (__bf16)b;
    return v.u;
}

// LDS-only drain barrier: global loads stay in flight across it (T4).
static __device__ __forceinline__ void lds_barrier() {
    asm volatile("s_waitcnt lgkmcnt(0)" ::: "memory");
    __builtin_amdgcn_s_barrier();
    __builtin_amdgcn_sched_barrier(0);
}

__global__ __launch_bounds__(512, 2)
void corr_mfma_kernel(const float* __restrict__ left,
                      const float* __restrict__ right,
                      float* __restrict__ out) {
    __shared__ uint32_t Lt[WSZ * RSTW];          // [w][cpair]    33280 B
    __shared__ uint32_t Rt[(WSZ + 80) * RSTW];   // [u+40][cpair] 39680 B

    const int t   = threadIdx.x;
    const int wv  = t >> 6;      // 0..7
    const int l   = t & 63;
    const int l15 = l & 15;
    const int l4  = l >> 4;      // 0..3
    const int b   = blockIdx.x >> 7;
    const int h   = blockIdx.x & 127;

    // ---- precompute flat staging map (chunk-invariant) ----
    // pair index pi = i*512 + t over [cpair 0..15][w 0..415]; 16*416 = 6656
    int gofs[13], ldsL[13];
    #pragma unroll
    for (int i = 0; i < 13; ++i) {
        const int pi = i * 512 + t;
        const int cp = pi / 416;          // 0..15 (magic-mul)
        const int w  = pi - 416 * cp;     // 0..415
        gofs[i] = 2 * cp * HW + w;        // channel 2cp at width w
        ldsL[i] = w * RSTW + cp;          // dword slot; R slot = ldsL + 40*RSTW
    }

    // ---- zero R halo rows once: u in [-40,0) and [416,456) -> rows 0..39, 456..495 ----
    #pragma unroll
    for (int i = 0; i < 4; ++i) {
        const int idx = i * 512 + t;      // 1600 dwords
        if (idx < 80 * RSTW) {
            const int row = idx / RSTW;
            const int col = idx - RSTW * row;
            const int phys = (row < 40) ? row : (row + WSZ);
            Rt[phys * RSTW + col] = 0u;
        }
    }

    f32x4 acc[4][6];
    #pragma unroll
    for (int ri = 0; ri < 4; ++ri)
        #pragma unroll
        for (int j = 0; j < 6; ++j)
            acc[ri][j] = (f32x4)0.0f;

    const size_t slab = ((size_t)b * CSZ) * HW + (size_t)h * WSZ;
    const float* Lp = left  + slab;
    const float* Rp = right + slab;

    float l0[13], l1[13], r0[13], r1[13];

    // ---- prologue: load + stage chunk 0 (contiguous 256B runs per instr) ----
    #pragma unroll
    for (int i = 0; i < 13; ++i) {
        l0[i] = Lp[gofs[i]];
        l1[i] = Lp[gofs[i] + HW];
        r0[i] = Rp[gofs[i]];
        r1[i] = Rp[gofs[i] + HW];
    }
    #pragma unroll
    for (int i = 0; i < 13; ++i) {
        Lt[ldsL[i]]              = pk2(l0[i], l1[i]);
        Rt[ldsL[i] + 40 * RSTW]  = pk2(r0[i], r1[i]);
    }
    lds_barrier();   // tile 0 visible (halo zeros too)

    for (int ck = 0; ck < NCHUNK; ++ck) {
        const bool more = (ck + 1 < NCHUNK);

        // ---- A) issue next-chunk loads early (in flight across MFMA + barriers) ----
        if (more) {
            const float* Lc = Lp + (size_t)(ck + 1) * 32 * HW;
            const float* Rc = Rp + (size_t)(ck + 1) * 32 * HW;
            #pragma unroll
            for (int i = 0; i < 13; ++i) {
                l0[i] = Lc[gofs[i]];
                l1[i] = Lc[gofs[i] + HW];
                r0[i] = Rc[gofs[i]];
                r1[i] = Rc[gofs[i] + HW];
            }
        }

        // ---- B) banded MFMA on current tile (validated mapping) ----
        const __bf16* Lb = (const __bf16*)Lt;
        const __bf16* Rb = (const __bf16*)Rt;
        #pragma unroll
        for (int ri = 0; ri < 4; ++ri) {
            const int row = wv + 8 * ri;
            if (row < 26) {
                const bf16x8 a = *(const bf16x8*)(Lb + (16 * row + l15) * 40 + 8 * l4);
                #pragma unroll
                for (int j = 0; j < 6; ++j) {
                    const bf16x8 bb = *(const bf16x8*)(Rb + (16 * (row + j) + l15) * 40 + 8 * l4);
                    acc[ri][j] = __builtin_amdgcn_mfma_f32_16x16x32_bf16(a, bb, acc[ri][j], 0, 0, 0);
                }
            }
        }

        if (more) {
            lds_barrier();   // everyone done reading tile ck

            // ---- C) pack + LDS write of tile ck+1 ----
            #pragma unroll
            for (int i = 0; i < 13; ++i) {
                Lt[ldsL[i]]             = pk2(l0[i], l1[i]);
                Rt[ldsL[i] + 40 * RSTW] = pk2(r0[i], r1[i]);
            }

            lds_barrier();   // tile ck+1 visible
        }
    }

    // ---- epilogue: C row m = 4*l4 + r (w off), col n = l15 (u off); d = 16j + n - m ----
    const float scale = 1.0f / 256.0f;
    #pragma unroll
    for (int ri = 0; ri < 4; ++ri) {
        const int row = wv + 8 * ri;
        if (row < 26) {
            const int wbase = 16 * row;
            #pragma unroll
            for (int j = 0; j < 6; ++j) {
                #pragma unroll
                for (int r = 0; r < 4; ++r) {
                    const int m = 4 * l4 + r;
                    const int d = 16 * j + l15 - m;
                    if ((unsigned)d < (unsigned)ND) {
                        out[(((size_t)b * ND + d) * HSZ + h) * WSZ + (wbase + m)] = acc[ri][j][r] * scale;
                    }
                }
            }
        }
    }
}

extern "C" void kernel_launch(void* const* d_in, const int* in_sizes, int n_in,
                              void* d_out, int out_size, void* d_ws, size_t ws_size,
                              hipStream_t stream) {
    const float* left  = (const float*)d_in[0];
    const float* right = (const float*)d_in[1];
    float* out = (float*)d_out;
    (void)in_sizes; (void)n_in; (void)out_size; (void)d_ws; (void)ws_size;
    corr_mfma_kernel<<<dim3(4 * 128), dim3(512), 0, stream>>>(left, right, out);
}

// Round 8
// 109.403 us; speedup vs baseline: 1.8296x; 1.0936x over previous
//
#include <hip/hip_runtime.h>
#include <hip/hip_bf16.h>
#include <stdint.h>

typedef __bf16 bf16x8 __attribute__((ext_vector_type(8)));
typedef float f32x4 __attribute__((ext_vector_type(4)));

#define MAXD 40
#define ND   81
#define CSZ  256
#define HSZ  128
#define WSZ  416
#define HW   (HSZ * WSZ)
#define NCHUNK 8

#define LSTR 448     // dwords per L channel row (416 data + shift room + align)
#define RSTR 544     // dwords per R channel row (496 data + shift room + align)
#define ROFF 14336   // dword offset of R region (= 32*448)
#define ESTR 420     // epilogue staging row stride (dwords)

// LDS-only drain barrier: global loads stay in flight across it (T4).
static __device__ __forceinline__ void lds_barrier() {
    asm volatile("s_waitcnt lgkmcnt(0)" ::: "memory");
    __builtin_amdgcn_s_barrier();
    __builtin_amdgcn_sched_barrier(0);
}

__global__ __launch_bounds__(512, 2)
void corr_mfma_kernel(const float* __restrict__ left,
                      const float* __restrict__ right,
                      float* __restrict__ out) {
    __shared__ float Sh[31744];   // 126976 B: L[32][448] | R[32][544], fp32 [c][w]

    const int t   = threadIdx.x;
    const int wv  = t >> 6;      // 0..7
    const int l   = t & 63;
    const int l15 = l & 15;
    const int l4  = l >> 4;      // 0..3
    const int b   = blockIdx.x >> 7;
    const int h   = blockIdx.x & 127;

    // ---- chunk-invariant staging map: 32 ch x 104 w-quads per input ----
    int gq[7], lwL[7], lwR[7];
    #pragma unroll
    for (int i = 0; i < 7; ++i) {
        const int qi = i * 512 + t;          // 0..3583 (mask at 3328)
        const int c  = qi / 104;
        const int q  = qi - 104 * c;
        const int sh = 8 * ((c >> 3) & 3);   // bank-spread shift per row
        gq[i]  = c * HW + 4 * q;
        lwL[i] = c * LSTR + sh + 4 * q;
        lwR[i] = ROFF + c * RSTR + sh + 40 + 4 * q;
    }

    // ---- zero R halo cols once (u in [-40,0) and [416,456)) ----
    #pragma unroll
    for (int i = 0; i < 5; ++i) {
        const int idx = i * 512 + t;         // 2560 slots = 32c x 80
        const int c   = idx / 80;
        const int k   = idx - 80 * c;
        const int col = (k < 40) ? k : (k + 416);
        Sh[ROFF + c * RSTR + 8 * ((c >> 3) & 3) + col] = 0.0f;
    }

    f32x4 acc[4][6];
    #pragma unroll
    for (int pi = 0; pi < 4; ++pi)
        #pragma unroll
        for (int a = 0; a < 6; ++a)
            acc[pi][a] = (f32x4)0.0f;

    const size_t slab = ((size_t)b * CSZ) * HW + (size_t)h * WSZ;
    const float* Lp = left  + slab;
    const float* Rp = right + slab;

    // per-lane fragment read bases
    const int LA = 3592 * l4 + l15;          // = l4*(8*LSTR+8) + l15
    const int LB = ROFF + 4360 * l4 + l15;   // = ROFF + l4*(8*RSTR+8) + l15

    f32x4 vL[7], vR[7];

    // ---- prologue: load + stage chunk 0 ----
    #pragma unroll
    for (int i = 0; i < 7; ++i) {
        const int qi = i * 512 + t;
        if (qi < 3328) {
            vL[i] = *(const f32x4*)(Lp + gq[i]);
            vR[i] = *(const f32x4*)(Rp + gq[i]);
        }
    }
    #pragma unroll
    for (int i = 0; i < 7; ++i) {
        const int qi = i * 512 + t;
        if (qi < 3328) {
            *(f32x4*)&Sh[lwL[i]] = vL[i];
            *(f32x4*)&Sh[lwR[i]] = vR[i];
        }
    }
    lds_barrier();   // tile 0 (and halo zeros) visible

    for (int ck = 0; ck < NCHUNK; ++ck) {
        const bool more = (ck + 1 < NCHUNK);

        // ---- A) issue next-chunk float4 loads early (1KB/instr, stay in flight) ----
        if (more) {
            const float* Lc = Lp + (size_t)(ck + 1) * 32 * HW;
            const float* Rc = Rp + (size_t)(ck + 1) * 32 * HW;
            #pragma unroll
            for (int i = 0; i < 7; ++i) {
                const int qi = i * 512 + t;
                if (qi < 3328) {
                    vL[i] = *(const f32x4*)(Lc + gq[i]);
                    vR[i] = *(const f32x4*)(Rc + gq[i]);
                }
            }
        }

        // ---- B) build fragments from LDS (transpose reads, 2-way free) + MFMA ----
        // wave owns p = 4*wv + pi, pi=0..3 (u-tile index); tiles (r = p-5+a, j = 5-a)
        bf16x8 bf[4];
        #pragma unroll
        for (int pi = 0; pi < 4; ++pi) {
            const int p = 4 * wv + pi;
            if (p <= 30) {
                #pragma unroll
                for (int kk = 0; kk < 8; ++kk)
                    bf[pi][kk] = (__bf16)Sh[LB + kk * RSTR + 16 * p];
            } else {
                #pragma unroll
                for (int kk = 0; kk < 8; ++kk) bf[pi][kk] = (__bf16)0.0f;
            }
        }
        #pragma unroll
        for (int s = 0; s < 9; ++s) {
            const int r = 4 * wv - 5 + s;
            if (r >= 0 && r <= 25) {
                bf16x8 af;
                #pragma unroll
                for (int kk = 0; kk < 8; ++kk)
                    af[kk] = (__bf16)Sh[LA + kk * LSTR + 16 * r];
                #pragma unroll
                for (int pi = 0; pi < 4; ++pi) {
                    const int a = s - pi;
                    if (a >= 0 && a <= 5)
                        acc[pi][a] = __builtin_amdgcn_mfma_f32_16x16x32_bf16(af, bf[pi], acc[pi][a], 0, 0, 0);
                }
            }
        }

        if (more) {
            lds_barrier();   // all waves done reading tile ck

            // ---- C) contiguous b128 LDS writes of tile ck+1 ----
            #pragma unroll
            for (int i = 0; i < 7; ++i) {
                const int qi = i * 512 + t;
                if (qi < 3328) {
                    *(f32x4*)&Sh[lwL[i]] = vL[i];
                    *(f32x4*)&Sh[lwR[i]] = vR[i];
                }
            }

            lds_barrier();   // tile ck+1 visible
        }
    }

    lds_barrier();   // MFMA reads done; Sh is now free for epilogue staging

    // ---- epilogue: stage C in LDS per d-half, then contiguous float4 stores ----
    const float scale = 1.0f / 256.0f;
    float* outp = out + ((size_t)b * ND) * HW + (size_t)h * WSZ;

    #pragma unroll
    for (int half = 0; half < 2; ++half) {
        const int d0 = half * 41;
        const int dN = half ? 40 : 41;

        // write phase: acc -> Sh[d - d0][w]
        #pragma unroll
        for (int pi = 0; pi < 4; ++pi) {
            #pragma unroll
            for (int a = 0; a < 6; ++a) {
                const int r = 4 * wv + pi - 5 + a;
                if (r >= 0 && r <= 25) {
                    const int j = 5 - a;
                    #pragma unroll
                    for (int rr = 0; rr < 4; ++rr) {
                        const int m = 4 * l4 + rr;
                        const int d = 16 * j + l15 - m;
                        if (d >= d0 && d < d0 + dN)
                            Sh[(d - d0) * ESTR + 16 * r + m] = acc[pi][a][rr] * scale;
                    }
                }
            }
        }
        lds_barrier();

        // store phase: contiguous dwordx4 to global
        #pragma unroll
        for (int i = 0; i < 9; ++i) {
            const int idx = i * 512 + t;
            if (idx < dN * 104) {
                const int d = idx / 104;
                const int q = idx - 104 * d;
                const f32x4 v = *(const f32x4*)&Sh[d * ESTR + 4 * q];
                *(f32x4*)(outp + (size_t)(d0 + d) * HW + 4 * q) = v;
            }
        }
        lds_barrier();   // half fully consumed before next half overwrites
    }
}

extern "C" void kernel_launch(void* const* d_in, const int* in_sizes, int n_in,
                              void* d_out, int out_size, void* d_ws, size_t ws_size,
                              hipStream_t stream) {
    const float* left  = (const float*)d_in[0];
    const float* right = (const float*)d_in[1];
    float* out = (float*)d_out;
    (void)in_sizes; (void)n_in; (void)out_size; (void)d_ws; (void)ws_size;
    corr_mfma_kernel<<<dim3(4 * 128), dim3(512), 0, stream>>>(left, right, out);
}